// Round 7
// baseline (293.916 us; speedup 1.0000x reference)
//
#include <hip/hip_runtime.h>
#include <hip/hip_bf16.h>
#include <hip/hip_fp16.h>
#include <math.h>

// B=8, H=16, N=1024, D=1024, hd=64
// ws layout (float units):
//   qpre f16 (B,H,N,64)   [0, 4M)        8M halfs   (normed+roped by gemm)
//   kpre f16 (B,H,N,64)   [4M, 8M)
//   vT   f16 (B,H,64,N)   [8M, 12M)      transposed per head
//   xb   bf16 [12M,16M)   (reused as ob after QKV gemm)
//   wqT  bf16 [16M,17.5M) ; woT bf16 [17.5M,18M)
// total 72 MB
#define QSZ 8388608  // halfs per q/k/v region

typedef short bf16x8 __attribute__((ext_vector_type(8)));
typedef _Float16 f16x8 __attribute__((ext_vector_type(8)));
typedef float f32x4 __attribute__((ext_vector_type(4)));

__device__ __forceinline__ unsigned short f2bf(float f) {
  __hip_bfloat16 h = __float2bfloat16(f);
  return *reinterpret_cast<unsigned short*>(&h);
}

__device__ __forceinline__ void gload16(const void* g, void* l) {
  __builtin_amdgcn_global_load_lds(
      (const __attribute__((address_space(1))) void*)g,
      (__attribute__((address_space(3))) void*)l, 16, 0, 0);
}

// ---------------------------------------------------------------------------
__global__ __launch_bounds__(256)
void cvt_bf16(const float* __restrict__ src, unsigned short* __restrict__ dst) {
  const int i = (blockIdx.x * 256 + threadIdx.x) * 8;
  const float4 a = *(const float4*)&src[i];
  const float4 b = *(const float4*)&src[i + 4];
  ushort4 lo, hi;
  lo.x = f2bf(a.x); lo.y = f2bf(a.y); lo.z = f2bf(a.z); lo.w = f2bf(a.w);
  hi.x = f2bf(b.x); hi.y = f2bf(b.y); hi.z = f2bf(b.z); hi.w = f2bf(b.w);
  *(ushort4*)&dst[i] = lo;
  *(ushort4*)&dst[i + 4] = hi;
}

// transpose+convert: src [1024,N] fp32 -> dst [N,1024] bf16
__global__ __launch_bounds__(256)
void cvt_t(const float* __restrict__ src, unsigned short* __restrict__ dst,
           const int N) {
  __shared__ unsigned short tile[32][33];
  const int k0 = blockIdx.y * 32, n0 = blockIdx.x * 32;
  const int t = threadIdx.x;
  const int r = t >> 3, c4 = (t & 7) * 4;
  const float4 v = *(const float4*)&src[(k0 + r) * N + n0 + c4];
  tile[r][c4 + 0] = f2bf(v.x);
  tile[r][c4 + 1] = f2bf(v.y);
  tile[r][c4 + 2] = f2bf(v.z);
  tile[r][c4 + 3] = f2bf(v.w);
  __syncthreads();
  ushort4 o;
  o.x = tile[c4 + 0][r];
  o.y = tile[c4 + 1][r];
  o.z = tile[c4 + 2][r];
  o.w = tile[c4 + 3][r];
  *(ushort4*)&dst[(long)(n0 + r) * 1024 + k0 + c4] = o;
}

// ---------------------------------------------------------------------------
// QKV GEMM: 256x128 block tile, BK=32, single-barrier dbuf, XCD stripe.
// 4 waves, each owns 128x64 (8x4 MFMA 16x16x32) -> 32 MFMA between barriers.
// Fused epilogue: RMSNorm + 2D-RoPE (+0.125 into q) -> q/k f16 (B,H,N,64);
// v -> f16 transposed (B,H,64,N).
// Grid: 768 flat; xcd=flat&7; bm=xcd*4+(j&3) (A stripe 2MB/XCD); bn=j>>2.
// ---------------------------------------------------------------------------
__global__ __launch_bounds__(256, 2)
void gemm_qkv(const unsigned short* __restrict__ A,
              const unsigned short* __restrict__ Bt,
              const float* __restrict__ bias, __half* __restrict__ Ch,
              const float* __restrict__ qsc, const float* __restrict__ ksc) {
  __shared__ __align__(16) unsigned short As[2][8192];  // 256 x 32
  __shared__ __align__(16) unsigned short Bs[2][4096];  // 128 x 32
  __shared__ float2 Tab[512];  // [pos 0..31][idx 0..15] cos/sin
  const int t = threadIdx.x;
  const int flat = blockIdx.x + blockIdx.y * 24;  // grid (24, 32)
  const int xcd = flat & 7, j = flat >> 3;        // j in [0,96)
  const int bm = xcd * 4 + (j & 3), bn = j >> 2;  // bm<32, bn<24
  const int w = t >> 6, lane = t & 63;
  const int wm = (w & 1) << 7, wn = (w >> 1) << 6;
  const int lm = lane & 15, lk = (lane >> 4) << 3;

  for (int e = t; e < 512; e += 256) {  // RoPE table (ready after 1st barrier)
    const int pos = e >> 4, idx = e & 15;
    const float invf = expf(-(float)idx * 0.57564627324851149f);
    const float ang = (float)pos * invf;
    Tab[e] = make_float2(cosf(ang), sinf(ang));
  }

  // staging: A 4 rounds x 64 rows, B 2 rounds x 64 rows; 16B/lane
  const unsigned short* aptr =
      A + (long)(bm * 256 + (t >> 2)) * 1024 + ((t & 3) << 3);
  const unsigned short* bptr =
      Bt + (long)(bn * 128 + (t >> 2)) * 1024 + ((t & 3) << 3);

  f32x4 acc[8][4] = {};

  // prologue: stage k-tile 0 into buffer 0
#pragma unroll
  for (int rr = 0; rr < 4; ++rr)
    gload16(aptr + rr * 64 * 1024, &As[0][rr * 2048 + t * 8]);
#pragma unroll
  for (int rr = 0; rr < 2; ++rr)
    gload16(bptr + rr * 64 * 1024, &Bs[0][rr * 2048 + t * 8]);

  for (int it = 0; it < 32; ++it) {
    const int cur = it & 1;
    __syncthreads();  // tile `it` staged for all waves
    if (it < 31) {    // prefetch tile it+1 into the other buffer
      const int nx = cur ^ 1;
      const int kk = (it + 1) * 32;
#pragma unroll
      for (int rr = 0; rr < 4; ++rr)
        gload16(aptr + rr * 64 * 1024 + kk, &As[nx][rr * 2048 + t * 8]);
#pragma unroll
      for (int rr = 0; rr < 2; ++rr)
        gload16(bptr + rr * 64 * 1024 + kk, &Bs[nx][rr * 2048 + t * 8]);
    }
    bf16x8 af[8], bfr[4];
#pragma unroll
    for (int mi = 0; mi < 8; ++mi)
      af[mi] = *(const bf16x8*)&As[cur][(wm + mi * 16 + lm) * 32 + lk];
#pragma unroll
    for (int ni = 0; ni < 4; ++ni)
      bfr[ni] = *(const bf16x8*)&Bs[cur][(wn + ni * 16 + lm) * 32 + lk];
#pragma unroll
    for (int mi = 0; mi < 8; ++mi)
#pragma unroll
      for (int ni = 0; ni < 4; ++ni)
        acc[mi][ni] = __builtin_amdgcn_mfma_f32_16x16x32_bf16(
            af[mi], bfr[ni], acc[mi][ni], 0, 0, 0);
  }

  const int r0 = (lane >> 4) << 2;  // q4*4
  const int nb = bn * 128 + wn;     // wave's col base
  const int tq = nb >> 10, h = (nb >> 6) & 15;

  if (tq == 2) {  // v: f16 transpose-scatter (B,H,64,N)
#pragma unroll
    for (int mi = 0; mi < 8; ++mi)
#pragma unroll
      for (int ni = 0; ni < 4; ++ni) {
        const int dd = ((nb + ni * 16 + lm) & 63);
        const float bv = bias[nb + ni * 16 + lm];
#pragma unroll
        for (int r = 0; r < 4; ++r) {
          const int m = bm * 256 + wm + mi * 16 + r0 + r;
          const int b = m >> 10, nn = m & 1023;
          Ch[2L * QSZ + ((long)((b * 16 + h) * 64 + dd)) * 1024 + nn] =
              __float2half(acc[mi][ni][r] + bv);
        }
      }
    return;
  }

  // q or k: RMSNorm + RoPE on f32 accs, then f16 store (B,H,N,64)
  const float* scp = (tq == 0) ? qsc : ksc;
  const float qmul = (tq == 0) ? 0.125f : 1.0f;  // fold hd^-0.5 into q
  float scv[4], bv[4];
#pragma unroll
  for (int ni = 0; ni < 4; ++ni) {
    scv[ni] = scp[ni * 16 + lm];
    bv[ni] = bias[nb + ni * 16 + lm];
  }
  __half* base = Ch + (long)tq * QSZ;
#pragma unroll
  for (int mi = 0; mi < 8; ++mi) {
#pragma unroll
    for (int r = 0; r < 4; ++r) {
      const float v0 = acc[mi][0][r] + bv[0];
      const float v1 = acc[mi][1][r] + bv[1];
      const float v2 = acc[mi][2][r] + bv[2];
      const float v3 = acc[mi][3][r] + bv[3];
      float ss = v0 * v0 + v1 * v1 + v2 * v2 + v3 * v3;
      ss += __shfl_xor(ss, 1, 64);
      ss += __shfl_xor(ss, 2, 64);
      ss += __shfl_xor(ss, 4, 64);
      ss += __shfl_xor(ss, 8, 64);
      const float inv = rsqrtf(ss * (1.0f / 64.0f) + 1e-6f) * qmul;
      const float a0 = v0 * inv * scv[0];
      const float a1 = v1 * inv * scv[1];
      const float a2 = v2 * inv * scv[2];
      const float a3 = v3 * inv * scv[3];
      const int m = bm * 256 + wm + mi * 16 + r0 + r;
      const int b = m >> 10, nn = m & 1023;
      const float2 tr = Tab[(nn >> 5) * 16 + lm];  // row-part angles
      const float2 tc = Tab[(nn & 31) * 16 + lm];  // col-part angles
      __half* row = base + ((long)((b * 16 + h) * 1024 + nn)) * 64 + lm;
      row[0]  = __float2half(a0 * tr.x - a2 * tr.y);
      row[16] = __float2half(a1 * tc.x - a3 * tc.y);
      row[32] = __float2half(a0 * tr.y + a2 * tr.x);
      row[48] = __float2half(a1 * tc.y + a3 * tc.x);
    }
  }
}

// ---------------------------------------------------------------------------
// Out-projection GEMM: 128x128 tile, BK=32, single-barrier dbuf, XCD stripe.
// ---------------------------------------------------------------------------
__global__ __launch_bounds__(256)
void gemm_out(const unsigned short* __restrict__ A,
              const unsigned short* __restrict__ Bt,
              const float* __restrict__ bias, float* __restrict__ Cf) {
  __shared__ __align__(16) unsigned short As[2][4096];
  __shared__ __align__(16) unsigned short Bs[2][4096];
  const int t = threadIdx.x;
  const int flat = blockIdx.x + blockIdx.y * 8;  // grid (8, 64)
  const int xcd = flat & 7, j = flat >> 3;
  const int bm = xcd * 8 + (j & 7), bn = j >> 3;
  const int w = t >> 6, lane = t & 63;
  const int wm = (w & 1) << 6, wn = (w >> 1) << 6;
  const int lm = lane & 15, lk = (lane >> 4) << 3;

  const unsigned short* aptr =
      A + (long)(bm * 128 + (t >> 2)) * 1024 + ((t & 3) << 3);
  const unsigned short* bptr =
      Bt + (long)(bn * 128 + (t >> 2)) * 1024 + ((t & 3) << 3);

  f32x4 acc[4][4] = {};

  gload16(aptr, &As[0][t * 8]);
  gload16(aptr + 64 * 1024, &As[0][2048 + t * 8]);
  gload16(bptr, &Bs[0][t * 8]);
  gload16(bptr + 64 * 1024, &Bs[0][2048 + t * 8]);

  for (int it = 0; it < 32; ++it) {
    const int cur = it & 1;
    __syncthreads();
    if (it < 31) {
      const int nx = cur ^ 1;
      const int kk = (it + 1) * 32;
      gload16(aptr + kk, &As[nx][t * 8]);
      gload16(aptr + 64 * 1024 + kk, &As[nx][2048 + t * 8]);
      gload16(bptr + kk, &Bs[nx][t * 8]);
      gload16(bptr + 64 * 1024 + kk, &Bs[nx][2048 + t * 8]);
    }
    bf16x8 af[4], bfr[4];
#pragma unroll
    for (int mi = 0; mi < 4; ++mi)
      af[mi] = *(const bf16x8*)&As[cur][(wm + mi * 16 + lm) * 32 + lk];
#pragma unroll
    for (int ni = 0; ni < 4; ++ni)
      bfr[ni] = *(const bf16x8*)&Bs[cur][(wn + ni * 16 + lm) * 32 + lk];
#pragma unroll
    for (int mi = 0; mi < 4; ++mi)
#pragma unroll
      for (int ni = 0; ni < 4; ++ni)
        acc[mi][ni] = __builtin_amdgcn_mfma_f32_16x16x32_bf16(
            af[mi], bfr[ni], acc[mi][ni], 0, 0, 0);
  }

  const int r0 = (lane >> 4) << 2;
  const int nb = bn * 128 + wn;
#pragma unroll
  for (int mi = 0; mi < 4; ++mi)
#pragma unroll
    for (int ni = 0; ni < 4; ++ni) {
      const int n = nb + ni * 16 + lm;
      const float bv = bias[n];
#pragma unroll
      for (int r = 0; r < 4; ++r)
        Cf[(long)(bm * 128 + wm + mi * 16 + r0 + r) * 1024 + n] =
            acc[mi][ni][r] + bv;
    }
}

// ---------------------------------------------------------------------------
// MFMA flash attention (f16), fixed-offset softmax, single-barrier dbuf,
// 128 Q-rows per block, XCD swizzle (16 heads/XCD -> 4MB K/V set in L2).
// ||q||=1 (0.125 folded), ||k||=8 -> s <= 8; p = exp(s-9).
// ---------------------------------------------------------------------------
__global__ __launch_bounds__(256)
void attn_mfma(const __half* __restrict__ qh, const __half* __restrict__ kh,
               const __half* __restrict__ vh, unsigned short* __restrict__ ob) {
  __shared__ __align__(16) __half Ks[2][4096];  // [krow][d] 64x64, swizzled
  __shared__ __align__(16) __half Vs[2][4096];  // [d][krow] 64x64, swizzled
  __shared__ __align__(16) __half Pl[4608];     // 4 waves x 16 x 72
  const int t = threadIdx.x;
  const int w = t >> 6, lane = t & 63;
  const int flat = blockIdx.x + blockIdx.y * 8;  // grid (8, 128)
  const int xcd = flat & 7, j = flat >> 3;       // j in [0,128)
  const int bh = xcd * 16 + (j >> 3);            // 16 heads per XCD
  const int qt = j & 7;                          // 128-row Q tile
  const int lm = lane & 15, q4 = lane >> 4;

  f16x8 qf[2][2];
#pragma unroll
  for (int g = 0; g < 2; ++g) {
    const __half* qrow =
        qh + ((long)(bh * 1024 + qt * 128 + g * 64 + w * 16 + lm)) * 64 +
        q4 * 8;
    qf[g][0] = *(const f16x8*)qrow;
    qf[g][1] = *(const f16x8*)(qrow + 32);
  }

  f32x4 o[2][4] = {};
  float l_r[2][4] = {};

  const int prow = t >> 3, pc = t & 7;
  const int scz = pc ^ (prow & 7);  // swizzled source chunk
  const __half* ksrc0 = kh + (long)(bh * 1024 + prow) * 64 + scz * 8;
  const __half* vsrc0 = vh + (long)(bh * 64 + prow) * 1024 + scz * 8;
  __half* Pw = Pl + w * 1152;

  gload16(ksrc0, &Ks[0][t * 8]);
  gload16(ksrc0 + 32 * 64, &Ks[0][2048 + t * 8]);
  gload16(vsrc0, &Vs[0][t * 8]);
  gload16(vsrc0 + 32 * 1024, &Vs[0][2048 + t * 8]);

  for (int kc = 0; kc < 16; ++kc) {
    const int cur = kc & 1;
    __syncthreads();

    if (kc < 15) {
      const int nx = cur ^ 1;
      const __half* ksrc = ksrc0 + (kc + 1) * 4096;
      const __half* vsrc = vsrc0 + (kc + 1) * 64;
      gload16(ksrc, &Ks[nx][t * 8]);
      gload16(ksrc + 32 * 64, &Ks[nx][2048 + t * 8]);
      gload16(vsrc, &Vs[nx][t * 8]);
      gload16(vsrc + 32 * 1024, &Vs[nx][2048 + t * 8]);
    }

#pragma unroll
    for (int g = 0; g < 2; ++g) {
      f32x4 s[4];
#pragma unroll
      for (int nt = 0; nt < 4; ++nt) {
        s[nt] = (f32x4){0.f, 0.f, 0.f, 0.f};
        const int kr = nt * 16 + lm;
#pragma unroll
        for (int ks = 0; ks < 2; ++ks) {
          const f16x8 kf = *(const f16x8*)&Ks[cur][kr * 64 +
                                            (((ks << 2) + q4) ^ (kr & 7)) * 8];
          s[nt] = __builtin_amdgcn_mfma_f32_16x16x32_f16(qf[g][ks], kf, s[nt],
                                                         0, 0, 0);
        }
      }

#pragma unroll
      for (int nt = 0; nt < 4; ++nt) {
#pragma unroll
        for (int r = 0; r < 4; ++r) {
          const float p = __expf(s[nt][r] - 9.0f);
          l_r[g][r] += p;
          Pw[(q4 * 4 + r) * 72 + nt * 16 + lm] = (__half)p;
        }
      }

#pragma unroll
      for (int ks2 = 0; ks2 < 2; ++ks2) {
        const f16x8 pf = *(const f16x8*)&Pw[lm * 72 + ks2 * 32 + q4 * 8];
#pragma unroll
        for (int nt = 0; nt < 4; ++nt) {
          const int dr = nt * 16 + lm;
          const f16x8 vf = *(const f16x8*)&Vs[cur][dr * 64 +
                                           (((ks2 << 2) + q4) ^ (dr & 7)) * 8];
          o[g][nt] = __builtin_amdgcn_mfma_f32_16x16x32_f16(pf, vf, o[g][nt],
                                                            0, 0, 0);
        }
      }
    }
  }

  const int b = bh >> 4, h = bh & 15;
#pragma unroll
  for (int g = 0; g < 2; ++g) {
#pragma unroll
    for (int r = 0; r < 4; ++r) {
      float l = l_r[g][r];
      l += __shfl_xor(l, 1, 64);
      l += __shfl_xor(l, 2, 64);
      l += __shfl_xor(l, 4, 64);
      l += __shfl_xor(l, 8, 64);
      const float linv = 1.0f / l;
      const long rowg =
          (long)(b * 1024 + qt * 128 + g * 64 + w * 16 + q4 * 4 + r) * 1024 +
          h * 64;
#pragma unroll
      for (int nt = 0; nt < 4; ++nt)
        ob[rowg + nt * 16 + lm] = f2bf(o[g][nt][r] * linv);
    }
  }
}

extern "C" void kernel_launch(void* const* d_in, const int* in_sizes, int n_in,
                              void* d_out, int out_size, void* d_ws,
                              size_t ws_size, hipStream_t stream) {
  const float* x    = (const float*)d_in[0];
  const float* Wqkv = (const float*)d_in[1];
  const float* bqkv = (const float*)d_in[2];
  const float* Wout = (const float*)d_in[3];
  const float* bout = (const float*)d_in[4];
  const float* qs   = (const float*)d_in[5];
  const float* ks   = (const float*)d_in[6];
  float* out = (float*)d_out;
  float* W = (float*)d_ws;  // 72 MB

  __half* qkvh = (__half*)W;            // q:0  k:+QSZ  vT:+2*QSZ (halfs)
  __half* qpre = qkvh;
  __half* kpre = qkvh + QSZ;
  __half* vT   = qkvh + 2 * QSZ;
  unsigned short* xb  = (unsigned short*)(W + 12582912);
  unsigned short* ob  = xb;
  unsigned short* wqT = (unsigned short*)(W + 16777216);
  unsigned short* woT = wqT + 3 * 1024 * 1024;

  cvt_bf16<<<4096, 256, 0, stream>>>(x, xb);
  cvt_t<<<dim3(96, 32), 256, 0, stream>>>(Wqkv, wqT, 3072);
  cvt_t<<<dim3(32, 32), 256, 0, stream>>>(Wout, woT, 1024);
  // 1) QKV projection + fused RMSNorm/RoPE (256x128 tiles)
  gemm_qkv<<<dim3(24, 32), 256, 0, stream>>>(xb, wqT, bqkv, qkvh, qs, ks);
  // 2) MFMA flash attention (128-row blocks) -> ob bf16 row-major
  attn_mfma<<<dim3(8, 128), 256, 0, stream>>>(qpre, kpre, vT, ob);
  // 3) output projection (128x128 tiles)
  gemm_out<<<dim3(8, 64), 256, 0, stream>>>(ob, woT, bout, out);
}